// Round 1
// baseline (467.439 us; speedup 1.0000x reference)
//
#include <hip/hip_runtime.h>
#include <hip/hip_bf16.h>
#include <math.h>

using bf16x8 = __attribute__((ext_vector_type(8))) __bf16;
using bf16x4 = __attribute__((ext_vector_type(4))) __bf16;
using f32x4  = __attribute__((ext_vector_type(4))) float;

static constexpr int S_ = 2048;
static constexpr float SCALE_L2E = 0.125f * 1.44269504088896340736f; // 1/sqrt(64) * log2(e)

__device__ __forceinline__ void gload16(const void* g, void* lds) {
    __builtin_amdgcn_global_load_lds((const __attribute__((address_space(1))) void*)g,
                                     (__attribute__((address_space(3))) void*)lds, 16, 0, 0);
}

__global__ void cast_f32_bf16(const float* __restrict__ src, __bf16* __restrict__ dst, int n4) {
    int i = blockIdx.x * blockDim.x + threadIdx.x;
    if (i < n4) {
        float4 v = reinterpret_cast<const float4*>(src)[i];
        bf16x4 o = { (__bf16)v.x, (__bf16)v.y, (__bf16)v.z, (__bf16)v.w };
        reinterpret_cast<bf16x4*>(dst)[i] = o;
    }
}

// C[m,n] = sum_k A[m,k] * Bt[n,k]   (A: MxK row-major bf16, Bt: NxK row-major bf16)
// EPI 0: QKV scatter epilogue (Q,K row-major per head; V transposed per head) + bias select
// EPI 1: fp32 output epilogue + bias
template <int EPI>
__global__ __launch_bounds__(256) void gemm_bt(
    const __bf16* __restrict__ A, const __bf16* __restrict__ Bt,
    const float* __restrict__ b0, const float* __restrict__ b1, const float* __restrict__ b2,
    __bf16* __restrict__ Qo, __bf16* __restrict__ Ko, __bf16* __restrict__ Vo,
    float* __restrict__ Fo, int K) {
    __shared__ __align__(16) __bf16 As[128 * 32];
    __shared__ __align__(16) __bf16 Bs[128 * 32];
    const int t = threadIdx.x, l = t & 63, w = t >> 6;
    const int m0 = blockIdx.y * 128, n0 = blockIdx.x * 128;
    const int wm = (w >> 1) * 64, wn = (w & 1) * 64;
    f32x4 acc[4][4] = {};

    const int row0 = t >> 2, cw0 = t & 3; // chunk t: 16B chunks, 4 per 32-elem row
    const __bf16* Ag0 = A + (size_t)(m0 + row0) * K + cw0 * 8;
    const __bf16* Ag1 = A + (size_t)(m0 + row0 + 64) * K + cw0 * 8;
    const __bf16* Bg0 = Bt + (size_t)(n0 + row0) * K + cw0 * 8;
    const __bf16* Bg1 = Bt + (size_t)(n0 + row0 + 64) * K + cw0 * 8;
    __bf16* Al0 = &As[(w * 64) * 8];
    __bf16* Al1 = &As[(w * 64 + 256) * 8];
    __bf16* Bl0 = &Bs[(w * 64) * 8];
    __bf16* Bl1 = &Bs[(w * 64 + 256) * 8];

    for (int k0 = 0; k0 < K; k0 += 32) {
        gload16(Ag0 + k0, Al0);
        gload16(Ag1 + k0, Al1);
        gload16(Bg0 + k0, Bl0);
        gload16(Bg1 + k0, Bl1);
        __syncthreads();
        bf16x8 af[4], bf[4];
#pragma unroll
        for (int i = 0; i < 4; ++i)
            af[i] = *reinterpret_cast<const bf16x8*>(&As[(wm + i * 16 + (l & 15)) * 32 + (l >> 4) * 8]);
#pragma unroll
        for (int j = 0; j < 4; ++j)
            bf[j] = *reinterpret_cast<const bf16x8*>(&Bs[(wn + j * 16 + (l & 15)) * 32 + (l >> 4) * 8]);
#pragma unroll
        for (int i = 0; i < 4; ++i)
#pragma unroll
            for (int j = 0; j < 4; ++j)
                acc[i][j] = __builtin_amdgcn_mfma_f32_16x16x32_bf16(af[i], bf[j], acc[i][j], 0, 0, 0);
        __syncthreads();
    }

    if (EPI == 0) {
        const int cls = n0 >> 10; // 0=Q 1=K 2=V (N=3072, tile 128 never straddles)
        const float* bias = (cls == 0) ? b0 : ((cls == 1) ? b1 : b2);
#pragma unroll
        for (int j = 0; j < 4; ++j) {
            const int e = n0 + wn + j * 16 + (l & 15);
            const int eh = e & 1023;
            const int h = eh >> 6, hd = eh & 63;
            const float bv = bias[eh];
#pragma unroll
            for (int i = 0; i < 4; ++i)
#pragma unroll
                for (int r = 0; r < 4; ++r) {
                    const int m = m0 + wm + i * 16 + ((l >> 4) << 2) + r;
                    const int b = m >> 11, s = m & 2047;
                    const float v = acc[i][j][r] + bv;
                    if (cls == 0)      Qo[((size_t)(b * 16 + h) * 2048 + s) * 64 + hd] = (__bf16)v;
                    else if (cls == 1) Ko[((size_t)(b * 16 + h) * 2048 + s) * 64 + hd] = (__bf16)v;
                    else               Vo[((size_t)(b * 16 + h) * 64 + hd) * 2048 + s] = (__bf16)v;
                }
        }
    } else {
#pragma unroll
        for (int j = 0; j < 4; ++j) {
            const int e = n0 + wn + j * 16 + (l & 15);
            const float bv = b0[e];
#pragma unroll
            for (int i = 0; i < 4; ++i)
#pragma unroll
                for (int r = 0; r < 4; ++r) {
                    const int m = m0 + wm + i * 16 + ((l >> 4) << 2) + r;
                    Fo[(size_t)m * 1024 + e] = acc[i][j][r] + bv;
                }
        }
    }
}

// Flash attention, causal. Q/K: [bh][s][64] bf16, VT: [bh][64][s] bf16, O: [b][s][h*64+hd] bf16.
// Block: 512 threads (8 waves), 128 q rows; KV tiles of 64 staged in LDS (XOR-swizzled rows).
__global__ __launch_bounds__(512) void attn_fwd(
    const __bf16* __restrict__ Qb, const __bf16* __restrict__ Kb,
    const __bf16* __restrict__ VTb, __bf16* __restrict__ Ob) {
    __shared__ __align__(16) __bf16 Ks[64 * 64];
    __shared__ __align__(16) __bf16 Vs[64 * 64];
    __shared__ __align__(16) __bf16 Ps[8 * 16 * 64];
    const int t = threadIdx.x, l = t & 63, w = t >> 6;
    const int qt = blockIdx.x, bh = blockIdx.y;
    const int q0 = qt * 128;
    const int qw = q0 + w * 16;

    const __bf16* Qg = Qb + (size_t)bh * S_ * 64;
    const __bf16* Kg = Kb + (size_t)bh * S_ * 64;
    const __bf16* Vg = VTb + (size_t)bh * 64 * S_;

    bf16x8 qf[2];
    {
        const int qrow = qw + (l & 15);
        qf[0] = *reinterpret_cast<const bf16x8*>(Qg + (size_t)qrow * 64 + (l >> 4) * 8);
        qf[1] = *reinterpret_cast<const bf16x8*>(Qg + (size_t)qrow * 64 + 32 + (l >> 4) * 8);
    }

    f32x4 o_acc[4] = {};
    float mrow[4] = { -INFINITY, -INFINITY, -INFINITY, -INFINITY };
    float lrow[4] = {};

    __bf16* Pw = &Ps[w * 16 * 64];

    // staging: 512 16B chunks each for K and VT; dest linear, source pre-swizzled (involution)
    const int srow = t >> 3, sc = t & 7;
    const __bf16* Ksrc = Kg + (size_t)srow * 64 + ((sc ^ (srow & 7)) * 8);
    const __bf16* Vsrc = Vg + (size_t)srow * S_ + ((sc ^ (srow & 7)) * 8);
    __bf16* Kl = &Ks[(w * 64) * 8];
    __bf16* Vl = &Vs[(w * 64) * 8];

    const int ktmax = 2 * qt + 1;
    for (int kt = 0; kt <= ktmax; ++kt) {
        gload16(Ksrc + (size_t)kt * 64 * 64, Kl);
        gload16(Vsrc + kt * 64, Vl);
        __syncthreads();
        if (kt * 64 <= qw + 15) { // wave not fully masked
            // S = Q K^T  (16q x 64kv)
            f32x4 sa[4] = {};
#pragma unroll
            for (int kk = 0; kk < 2; ++kk) {
#pragma unroll
                for (int j = 0; j < 4; ++j) {
                    const int row = j * 16 + (l & 15);
                    int byt = row * 128 + (kk * 32 + (l >> 4) * 8) * 2;
                    byt ^= (row & 7) << 4;
                    bf16x8 kf = *reinterpret_cast<const bf16x8*>(reinterpret_cast<const char*>(Ks) + byt);
                    sa[j] = __builtin_amdgcn_mfma_f32_16x16x32_bf16(qf[kk], kf, sa[j], 0, 0, 0);
                }
            }
            const bool bnd = (kt * 64 + 63) > qw;
            float p[4][4];
#pragma unroll
            for (int j = 0; j < 4; ++j) {
                const int kvg = kt * 64 + j * 16 + (l & 15);
#pragma unroll
                for (int r = 0; r < 4; ++r) {
                    float x = sa[j][r] * SCALE_L2E;
                    if (bnd && kvg > (qw + ((l >> 4) << 2) + r)) x = -INFINITY;
                    p[j][r] = x;
                }
            }
#pragma unroll
            for (int r = 0; r < 4; ++r) {
                float mt = fmaxf(fmaxf(p[0][r], p[1][r]), fmaxf(p[2][r], p[3][r]));
                mt = fmaxf(mt, __shfl_xor(mt, 1));
                mt = fmaxf(mt, __shfl_xor(mt, 2));
                mt = fmaxf(mt, __shfl_xor(mt, 4));
                mt = fmaxf(mt, __shfl_xor(mt, 8));
                const float mn = fmaxf(mrow[r], mt);
                const float al = exp2f(mrow[r] - mn);
                mrow[r] = mn;
                float sum = 0.f;
#pragma unroll
                for (int j = 0; j < 4; ++j) {
                    float e = exp2f(p[j][r] - mn);
                    p[j][r] = e;
                    sum += e;
                }
                sum += __shfl_xor(sum, 1);
                sum += __shfl_xor(sum, 2);
                sum += __shfl_xor(sum, 4);
                sum += __shfl_xor(sum, 8);
                lrow[r] = lrow[r] * al + sum;
#pragma unroll
                for (int j = 0; j < 4; ++j) o_acc[j][r] *= al;
            }
            // write P (bf16) into per-wave LDS, swizzled rows
#pragma unroll
            for (int j = 0; j < 4; ++j)
#pragma unroll
                for (int r = 0; r < 4; ++r) {
                    const int qr = ((l >> 4) << 2) + r;
                    int byt = qr * 128 + (j * 16 + (l & 15)) * 2;
                    byt ^= (qr & 7) << 4;
                    *reinterpret_cast<__bf16*>(reinterpret_cast<char*>(Pw) + byt) = (__bf16)p[j][r];
                }
            // O += P V
#pragma unroll
            for (int kk = 0; kk < 2; ++kk) {
                int pb = (l & 15) * 128 + (kk * 32 + (l >> 4) * 8) * 2;
                pb ^= (l & 7) << 4; // q = l&15, (q&7)<<4
                bf16x8 pf = *reinterpret_cast<const bf16x8*>(reinterpret_cast<const char*>(Pw) + pb);
#pragma unroll
                for (int j = 0; j < 4; ++j) {
                    const int hd = j * 16 + (l & 15);
                    int vb = hd * 128 + (kk * 32 + (l >> 4) * 8) * 2;
                    vb ^= (hd & 7) << 4;
                    bf16x8 vf = *reinterpret_cast<const bf16x8*>(reinterpret_cast<const char*>(Vs) + vb);
                    o_acc[j] = __builtin_amdgcn_mfma_f32_16x16x32_bf16(pf, vf, o_acc[j], 0, 0, 0);
                }
            }
        }
        __syncthreads();
    }
    const int b = bh >> 4, h = bh & 15;
#pragma unroll
    for (int r = 0; r < 4; ++r) {
        const float inv = 1.0f / lrow[r];
        const int q = qw + ((l >> 4) << 2) + r;
#pragma unroll
        for (int j = 0; j < 4; ++j)
            Ob[(size_t)(b * 2048 + q) * 1024 + h * 64 + j * 16 + (l & 15)] = (__bf16)(o_acc[j][r] * inv);
    }
}

extern "C" void kernel_launch(void* const* d_in, const int* in_sizes, int n_in,
                              void* d_out, int out_size, void* d_ws, size_t ws_size,
                              hipStream_t stream) {
    const float* x  = (const float*)d_in[0];
    const float* wq = (const float*)d_in[2];
    const float* bq = (const float*)d_in[3];
    const float* wk = (const float*)d_in[4];
    const float* bk = (const float*)d_in[5];
    const float* wv = (const float*)d_in[6];
    const float* bv = (const float*)d_in[7];
    const float* wo = (const float*)d_in[8];
    const float* bo = (const float*)d_in[9];
    float* out = (float*)d_out;

    char* ws = (char*)d_ws;
    __bf16* xb   = (__bf16*)(ws);                 // 8192x1024        = 16,777,216 B
    __bf16* wqkv = (__bf16*)(ws + 16777216);      // 3072x1024        =  6,291,456 B
    __bf16* wob  = (__bf16*)(ws + 23068672);      // 1024x1024        =  2,097,152 B
    __bf16* Qb   = (__bf16*)(ws + 25165824);      // 64x2048x64       = 16,777,216 B
    __bf16* Kb   = (__bf16*)(ws + 41943040);      // 64x2048x64       = 16,777,216 B
    __bf16* VTb  = (__bf16*)(ws + 58720256);      // 64x64x2048       = 16,777,216 B
    __bf16* Ob   = (__bf16*)(ws + 75497472);      // 8192x1024        = 16,777,216 B

    cast_f32_bf16<<<8192, 256, 0, stream>>>(x, xb, 2097152);
    cast_f32_bf16<<<1024, 256, 0, stream>>>(wq, wqkv, 262144);
    cast_f32_bf16<<<1024, 256, 0, stream>>>(wk, wqkv + 1048576, 262144);
    cast_f32_bf16<<<1024, 256, 0, stream>>>(wv, wqkv + 2097152, 262144);
    cast_f32_bf16<<<1024, 256, 0, stream>>>(wo, wob, 262144);

    gemm_bt<0><<<dim3(24, 64), 256, 0, stream>>>(xb, wqkv, bq, bk, bv, Qb, Kb, VTb, nullptr, 1024);
    attn_fwd<<<dim3(16, 64), 512, 0, stream>>>(Qb, Kb, VTb, Ob);
    gemm_bt<1><<<dim3(8, 64), 256, 0, stream>>>(Ob, wob, bo, nullptr, nullptr, nullptr, nullptr, nullptr, out, 1024);
}

// Round 2
// 344.105 us; speedup vs baseline: 1.3584x; 1.3584x over previous
//
#include <hip/hip_runtime.h>
#include <hip/hip_bf16.h>
#include <math.h>

using bf16x8 = __attribute__((ext_vector_type(8))) __bf16;
using bf16x4 = __attribute__((ext_vector_type(4))) __bf16;
using f32x4  = __attribute__((ext_vector_type(4))) float;

static constexpr int S_ = 2048;
static constexpr float SCALE_L2E = 0.125f * 1.44269504088896340736f; // 1/sqrt(64) * log2(e)

__device__ __forceinline__ void gload16(const void* g, void* lds) {
    __builtin_amdgcn_global_load_lds((const __attribute__((address_space(1))) void*)g,
                                     (__attribute__((address_space(3))) void*)lds, 16, 0, 0);
}

__global__ void cast_f32_bf16(const float* __restrict__ src, __bf16* __restrict__ dst, int n4) {
    int i = blockIdx.x * blockDim.x + threadIdx.x;
    if (i < n4) {
        float4 v = reinterpret_cast<const float4*>(src)[i];
        bf16x4 o = { (__bf16)v.x, (__bf16)v.y, (__bf16)v.z, (__bf16)v.w };
        reinterpret_cast<bf16x4*>(dst)[i] = o;
    }
}

// C[m,n] = sum_k A[m,k] * Bt[n,k]   (A: MxK row-major bf16, Bt: NxK row-major bf16)
// EPI 0: QKV scatter epilogue (Q,K row-major per head; V transposed per head) + bias select
// EPI 1: fp32 output epilogue + bias
template <int EPI>
__global__ __launch_bounds__(256) void gemm_bt(
    const __bf16* __restrict__ A, const __bf16* __restrict__ Bt,
    const float* __restrict__ b0, const float* __restrict__ b1, const float* __restrict__ b2,
    __bf16* __restrict__ Qo, __bf16* __restrict__ Ko, __bf16* __restrict__ Vo,
    float* __restrict__ Fo, int K) {
    __shared__ __align__(16) __bf16 As[128 * 32];
    __shared__ __align__(16) __bf16 Bs[128 * 32];
    const int t = threadIdx.x, l = t & 63, w = t >> 6;
    const int m0 = blockIdx.y * 128, n0 = blockIdx.x * 128;
    const int wm = (w >> 1) * 64, wn = (w & 1) * 64;
    f32x4 acc[4][4] = {};

    const int row0 = t >> 2, cw0 = t & 3; // chunk t: 16B chunks, 4 per 32-elem row
    const __bf16* Ag0 = A + (size_t)(m0 + row0) * K + cw0 * 8;
    const __bf16* Ag1 = A + (size_t)(m0 + row0 + 64) * K + cw0 * 8;
    const __bf16* Bg0 = Bt + (size_t)(n0 + row0) * K + cw0 * 8;
    const __bf16* Bg1 = Bt + (size_t)(n0 + row0 + 64) * K + cw0 * 8;
    __bf16* Al0 = &As[(w * 64) * 8];
    __bf16* Al1 = &As[(w * 64 + 256) * 8];
    __bf16* Bl0 = &Bs[(w * 64) * 8];
    __bf16* Bl1 = &Bs[(w * 64 + 256) * 8];

    for (int k0 = 0; k0 < K; k0 += 32) {
        gload16(Ag0 + k0, Al0);
        gload16(Ag1 + k0, Al1);
        gload16(Bg0 + k0, Bl0);
        gload16(Bg1 + k0, Bl1);
        __syncthreads();
        bf16x8 af[4], bf[4];
#pragma unroll
        for (int i = 0; i < 4; ++i)
            af[i] = *reinterpret_cast<const bf16x8*>(&As[(wm + i * 16 + (l & 15)) * 32 + (l >> 4) * 8]);
#pragma unroll
        for (int j = 0; j < 4; ++j)
            bf[j] = *reinterpret_cast<const bf16x8*>(&Bs[(wn + j * 16 + (l & 15)) * 32 + (l >> 4) * 8]);
#pragma unroll
        for (int i = 0; i < 4; ++i)
#pragma unroll
            for (int j = 0; j < 4; ++j)
                acc[i][j] = __builtin_amdgcn_mfma_f32_16x16x32_bf16(af[i], bf[j], acc[i][j], 0, 0, 0);
        __syncthreads();
    }

    if (EPI == 0) {
        const int cls = n0 >> 10; // 0=Q 1=K 2=V (N=3072, tile 128 never straddles)
        const float* bias = (cls == 0) ? b0 : ((cls == 1) ? b1 : b2);
#pragma unroll
        for (int j = 0; j < 4; ++j) {
            const int e = n0 + wn + j * 16 + (l & 15);
            const int eh = e & 1023;
            const int h = eh >> 6, hd = eh & 63;
            const float bv = bias[eh];
#pragma unroll
            for (int i = 0; i < 4; ++i)
#pragma unroll
                for (int r = 0; r < 4; ++r) {
                    const int m = m0 + wm + i * 16 + ((l >> 4) << 2) + r;
                    const int b = m >> 11, s = m & 2047;
                    const float v = acc[i][j][r] + bv;
                    if (cls == 0)      Qo[((size_t)(b * 16 + h) * 2048 + s) * 64 + hd] = (__bf16)v;
                    else if (cls == 1) Ko[((size_t)(b * 16 + h) * 2048 + s) * 64 + hd] = (__bf16)v;
                    else               Vo[((size_t)(b * 16 + h) * 64 + hd) * 2048 + s] = (__bf16)v;
                }
        }
    } else {
#pragma unroll
        for (int j = 0; j < 4; ++j) {
            const int e = n0 + wn + j * 16 + (l & 15);
            const float bv = b0[e];
#pragma unroll
            for (int i = 0; i < 4; ++i)
#pragma unroll
                for (int r = 0; r < 4; ++r) {
                    const int m = m0 + wm + i * 16 + ((l >> 4) << 2) + r;
                    Fo[(size_t)m * 1024 + e] = acc[i][j][r] + bv;
                }
        }
    }
}

// Flash attention, causal. Q/K: [bh][s][64] bf16, VT: [bh][64][s] bf16, O: [b][s][h*64+hd] bf16.
// Block: 512 threads (8 waves), 128 q rows; KV tiles of 64, DOUBLE-BUFFERED in LDS
// (XOR-swizzled rows), counted-vmcnt pipeline (T3+T4 2-phase), heavy blocks launched first.
__global__ __launch_bounds__(512) void attn_fwd(
    const __bf16* __restrict__ Qb, const __bf16* __restrict__ Kb,
    const __bf16* __restrict__ VTb, __bf16* __restrict__ Ob) {
    __shared__ __align__(16) __bf16 Ks[2][64 * 64];
    __shared__ __align__(16) __bf16 Vs[2][64 * 64];
    __shared__ __align__(16) __bf16 Ps[8 * 16 * 64];
    const int t = threadIdx.x, l = t & 63, w = t >> 6;
    const int qt = (int)gridDim.x - 1 - (int)blockIdx.x; // reversed: heavy (large-kt) blocks first
    const int bh = blockIdx.y;
    const int qw = qt * 128 + w * 16;

    const __bf16* Qg = Qb + (size_t)bh * S_ * 64;
    const __bf16* Kg = Kb + (size_t)bh * S_ * 64;
    const __bf16* Vg = VTb + (size_t)bh * 64 * S_;

    bf16x8 qf[2];
    {
        const int qrow = qw + (l & 15);
        qf[0] = *reinterpret_cast<const bf16x8*>(Qg + (size_t)qrow * 64 + (l >> 4) * 8);
        qf[1] = *reinterpret_cast<const bf16x8*>(Qg + (size_t)qrow * 64 + 32 + (l >> 4) * 8);
    }

    f32x4 o_acc[4] = {};
    float mrow[4] = { -INFINITY, -INFINITY, -INFINITY, -INFINITY };
    float lrow[4] = {};

    __bf16* Pw = &Ps[w * 16 * 64];

    // staging: 512 16B chunks each for K and VT; dest linear, source pre-swizzled (involution)
    const int srow = t >> 3, sc = t & 7;
    const __bf16* Ksrc = Kg + (size_t)srow * 64 + ((sc ^ (srow & 7)) * 8);
    const __bf16* Vsrc = Vg + (size_t)srow * S_ + ((sc ^ (srow & 7)) * 8);
    __bf16* Kd0 = &Ks[0][(w * 64) * 8];
    __bf16* Kd1 = &Ks[1][(w * 64) * 8];
    __bf16* Vd0 = &Vs[0][(w * 64) * 8];
    __bf16* Vd1 = &Vs[1][(w * 64) * 8];

    const int ktmax = 2 * qt + 1;
    // prologue: stage tile 0 into buffer 0
    gload16(Ksrc, Kd0);
    gload16(Vsrc, Vd0);
    int cur = 0;
    for (int kt = 0; kt <= ktmax; ++kt) {
        if (kt < ktmax) {
            // issue next tile into the other buffer; keep its 2 loads in flight
            gload16(Ksrc + (size_t)(kt + 1) * 4096, (cur == 0) ? Kd1 : Kd0);
            gload16(Vsrc + (kt + 1) * 64, (cur == 0) ? Vd1 : Vd0);
            asm volatile("s_waitcnt vmcnt(2)" ::: "memory"); // tile kt's loads complete
        } else {
            asm volatile("s_waitcnt vmcnt(0)" ::: "memory");
        }
        __builtin_amdgcn_s_barrier();
        const char* kb = (cur == 0) ? (const char*)Ks[0] : (const char*)Ks[1];
        const char* vb = (cur == 0) ? (const char*)Vs[0] : (const char*)Vs[1];
        if (kt * 64 <= qw + 15) { // wave not fully masked
            // S = Q K^T  (16q x 64kv)
            f32x4 sa[4] = {};
            __builtin_amdgcn_s_setprio(1);
#pragma unroll
            for (int kk = 0; kk < 2; ++kk) {
#pragma unroll
                for (int j = 0; j < 4; ++j) {
                    const int row = j * 16 + (l & 15);
                    int byt = row * 128 + (kk * 32 + (l >> 4) * 8) * 2;
                    byt ^= (row & 7) << 4;
                    bf16x8 kf = *reinterpret_cast<const bf16x8*>(kb + byt);
                    sa[j] = __builtin_amdgcn_mfma_f32_16x16x32_bf16(qf[kk], kf, sa[j], 0, 0, 0);
                }
            }
            __builtin_amdgcn_s_setprio(0);
            const bool bnd = (kt * 64 + 63) > qw;
            float p[4][4];
#pragma unroll
            for (int j = 0; j < 4; ++j) {
                const int kvg = kt * 64 + j * 16 + (l & 15);
#pragma unroll
                for (int r = 0; r < 4; ++r) {
                    float x = sa[j][r] * SCALE_L2E;
                    if (bnd && kvg > (qw + ((l >> 4) << 2) + r)) x = -INFINITY;
                    p[j][r] = x;
                }
            }
#pragma unroll
            for (int r = 0; r < 4; ++r) {
                float mt = fmaxf(fmaxf(p[0][r], p[1][r]), fmaxf(p[2][r], p[3][r]));
                mt = fmaxf(mt, __shfl_xor(mt, 1));
                mt = fmaxf(mt, __shfl_xor(mt, 2));
                mt = fmaxf(mt, __shfl_xor(mt, 4));
                mt = fmaxf(mt, __shfl_xor(mt, 8));
                const float mn = fmaxf(mrow[r], mt);
                const float al = exp2f(mrow[r] - mn);
                mrow[r] = mn;
                float sum = 0.f;
#pragma unroll
                for (int j = 0; j < 4; ++j) {
                    float e = exp2f(p[j][r] - mn);
                    p[j][r] = e;
                    sum += e;
                }
                sum += __shfl_xor(sum, 1);
                sum += __shfl_xor(sum, 2);
                sum += __shfl_xor(sum, 4);
                sum += __shfl_xor(sum, 8);
                lrow[r] = lrow[r] * al + sum;
#pragma unroll
                for (int j = 0; j < 4; ++j) o_acc[j][r] *= al;
            }
            // write P (bf16) into per-wave LDS, swizzled rows
#pragma unroll
            for (int j = 0; j < 4; ++j)
#pragma unroll
                for (int r = 0; r < 4; ++r) {
                    const int qr = ((l >> 4) << 2) + r;
                    int byt = qr * 128 + (j * 16 + (l & 15)) * 2;
                    byt ^= (qr & 7) << 4;
                    *reinterpret_cast<__bf16*>(reinterpret_cast<char*>(Pw) + byt) = (__bf16)p[j][r];
                }
            // O += P V
            __builtin_amdgcn_s_setprio(1);
#pragma unroll
            for (int kk = 0; kk < 2; ++kk) {
                int pb = (l & 15) * 128 + (kk * 32 + (l >> 4) * 8) * 2;
                pb ^= (l & 7) << 4; // q = l&15, (q&7)<<4
                bf16x8 pf = *reinterpret_cast<const bf16x8*>(reinterpret_cast<const char*>(Pw) + pb);
#pragma unroll
                for (int j = 0; j < 4; ++j) {
                    const int hd = j * 16 + (l & 15);
                    int vb2 = hd * 128 + (kk * 32 + (l >> 4) * 8) * 2;
                    vb2 ^= (hd & 7) << 4;
                    bf16x8 vf = *reinterpret_cast<const bf16x8*>(vb + vb2);
                    o_acc[j] = __builtin_amdgcn_mfma_f32_16x16x32_bf16(pf, vf, o_acc[j], 0, 0, 0);
                }
            }
            __builtin_amdgcn_s_setprio(0);
        }
        __builtin_amdgcn_s_barrier(); // all reads of buf[cur] done before it is re-staged
        cur ^= 1;
    }
    const int b = bh >> 4, h = bh & 15;
#pragma unroll
    for (int r = 0; r < 4; ++r) {
        const float inv = 1.0f / lrow[r];
        const int q = qw + ((l >> 4) << 2) + r;
#pragma unroll
        for (int j = 0; j < 4; ++j)
            Ob[(size_t)(b * 2048 + q) * 1024 + h * 64 + j * 16 + (l & 15)] = (__bf16)(o_acc[j][r] * inv);
    }
}

extern "C" void kernel_launch(void* const* d_in, const int* in_sizes, int n_in,
                              void* d_out, int out_size, void* d_ws, size_t ws_size,
                              hipStream_t stream) {
    const float* x  = (const float*)d_in[0];
    const float* wq = (const float*)d_in[2];
    const float* bq = (const float*)d_in[3];
    const float* wk = (const float*)d_in[4];
    const float* bk = (const float*)d_in[5];
    const float* wv = (const float*)d_in[6];
    const float* bv = (const float*)d_in[7];
    const float* wo = (const float*)d_in[8];
    const float* bo = (const float*)d_in[9];
    float* out = (float*)d_out;

    char* ws = (char*)d_ws;
    __bf16* xb   = (__bf16*)(ws);                 // 8192x1024        = 16,777,216 B
    __bf16* wqkv = (__bf16*)(ws + 16777216);      // 3072x1024        =  6,291,456 B
    __bf16* wob  = (__bf16*)(ws + 23068672);      // 1024x1024        =  2,097,152 B
    __bf16* Qb   = (__bf16*)(ws + 25165824);      // 64x2048x64       = 16,777,216 B
    __bf16* Kb   = (__bf16*)(ws + 41943040);      // 64x2048x64       = 16,777,216 B
    __bf16* VTb  = (__bf16*)(ws + 58720256);      // 64x64x2048       = 16,777,216 B
    __bf16* Ob   = (__bf16*)(ws + 75497472);      // 8192x1024        = 16,777,216 B

    cast_f32_bf16<<<8192, 256, 0, stream>>>(x, xb, 2097152);
    cast_f32_bf16<<<1024, 256, 0, stream>>>(wq, wqkv, 262144);
    cast_f32_bf16<<<1024, 256, 0, stream>>>(wk, wqkv + 1048576, 262144);
    cast_f32_bf16<<<1024, 256, 0, stream>>>(wv, wqkv + 2097152, 262144);
    cast_f32_bf16<<<1024, 256, 0, stream>>>(wo, wob, 262144);

    gemm_bt<0><<<dim3(24, 64), 256, 0, stream>>>(xb, wqkv, bq, bk, bv, Qb, Kb, VTb, nullptr, 1024);
    attn_fwd<<<dim3(16, 64), 512, 0, stream>>>(Qb, Kb, VTb, Ob);
    gemm_bt<1><<<dim3(8, 64), 256, 0, stream>>>(Ob, wob, bo, nullptr, nullptr, nullptr, nullptr, nullptr, out, 1024);
}

// Round 3
// 287.574 us; speedup vs baseline: 1.6255x; 1.1966x over previous
//
#include <hip/hip_runtime.h>
#include <hip/hip_bf16.h>
#include <math.h>

using bf16x8 = __attribute__((ext_vector_type(8))) __bf16;
using bf16x4 = __attribute__((ext_vector_type(4))) __bf16;
using f32x4  = __attribute__((ext_vector_type(4))) float;

static constexpr int S_ = 2048;
static constexpr float SCALE_L2E = 0.125f * 1.44269504088896340736f; // 1/sqrt(64) * log2(e)

__device__ __forceinline__ void gload16(const void* g, void* lds) {
    __builtin_amdgcn_global_load_lds((const __attribute__((address_space(1))) void*)g,
                                     (__attribute__((address_space(3))) void*)lds, 16, 0, 0);
}

__global__ void cast_f32_bf16(const float* __restrict__ src, __bf16* __restrict__ dst, int n4) {
    int i = blockIdx.x * blockDim.x + threadIdx.x;
    if (i < n4) {
        float4 v = reinterpret_cast<const float4*>(src)[i];
        bf16x4 o = { (__bf16)v.x, (__bf16)v.y, (__bf16)v.z, (__bf16)v.w };
        reinterpret_cast<bf16x4*>(dst)[i] = o;
    }
}

// C[m,n] = sum_k A[m,k] * Bt[n,k]   (A: MxK row-major bf16, Bt: NxK row-major bf16)
// EPI 0: QKV scatter epilogue (Q row-major pre-scaled by 1/sqrt(d)*log2e; K row-major;
//        V transposed per head) + bias select
// EPI 1: fp32 output epilogue + bias
template <int EPI>
__global__ __launch_bounds__(256) void gemm_bt(
    const __bf16* __restrict__ A, const __bf16* __restrict__ Bt,
    const float* __restrict__ b0, const float* __restrict__ b1, const float* __restrict__ b2,
    __bf16* __restrict__ Qo, __bf16* __restrict__ Ko, __bf16* __restrict__ Vo,
    float* __restrict__ Fo, int K) {
    __shared__ __align__(16) __bf16 As[128 * 32];
    __shared__ __align__(16) __bf16 Bs[128 * 32];
    const int t = threadIdx.x, l = t & 63, w = t >> 6;
    const int m0 = blockIdx.y * 128, n0 = blockIdx.x * 128;
    const int wm = (w >> 1) * 64, wn = (w & 1) * 64;
    f32x4 acc[4][4] = {};

    const int row0 = t >> 2, cw0 = t & 3; // chunk t: 16B chunks, 4 per 32-elem row
    const __bf16* Ag0 = A + (size_t)(m0 + row0) * K + cw0 * 8;
    const __bf16* Ag1 = A + (size_t)(m0 + row0 + 64) * K + cw0 * 8;
    const __bf16* Bg0 = Bt + (size_t)(n0 + row0) * K + cw0 * 8;
    const __bf16* Bg1 = Bt + (size_t)(n0 + row0 + 64) * K + cw0 * 8;
    __bf16* Al0 = &As[(w * 64) * 8];
    __bf16* Al1 = &As[(w * 64 + 256) * 8];
    __bf16* Bl0 = &Bs[(w * 64) * 8];
    __bf16* Bl1 = &Bs[(w * 64 + 256) * 8];

    for (int k0 = 0; k0 < K; k0 += 32) {
        gload16(Ag0 + k0, Al0);
        gload16(Ag1 + k0, Al1);
        gload16(Bg0 + k0, Bl0);
        gload16(Bg1 + k0, Bl1);
        __syncthreads();
        bf16x8 af[4], bf[4];
#pragma unroll
        for (int i = 0; i < 4; ++i)
            af[i] = *reinterpret_cast<const bf16x8*>(&As[(wm + i * 16 + (l & 15)) * 32 + (l >> 4) * 8]);
#pragma unroll
        for (int j = 0; j < 4; ++j)
            bf[j] = *reinterpret_cast<const bf16x8*>(&Bs[(wn + j * 16 + (l & 15)) * 32 + (l >> 4) * 8]);
#pragma unroll
        for (int i = 0; i < 4; ++i)
#pragma unroll
            for (int j = 0; j < 4; ++j)
                acc[i][j] = __builtin_amdgcn_mfma_f32_16x16x32_bf16(af[i], bf[j], acc[i][j], 0, 0, 0);
        __syncthreads();
    }

    if (EPI == 0) {
        const int cls = n0 >> 10; // 0=Q 1=K 2=V (N=3072, tile 128 never straddles)
        const float* bias = (cls == 0) ? b0 : ((cls == 1) ? b1 : b2);
#pragma unroll
        for (int j = 0; j < 4; ++j) {
            const int e = n0 + wn + j * 16 + (l & 15);
            const int eh = e & 1023;
            const int h = eh >> 6, hd = eh & 63;
            const float bv = bias[eh];
#pragma unroll
            for (int i = 0; i < 4; ++i)
#pragma unroll
                for (int r = 0; r < 4; ++r) {
                    const int m = m0 + wm + i * 16 + ((l >> 4) << 2) + r;
                    const int b = m >> 11, s = m & 2047;
                    float v = acc[i][j][r] + bv;
                    if (cls == 0) {
                        v *= SCALE_L2E; // fold softmax scale into Q (fp32, pre-cast)
                        Qo[((size_t)(b * 16 + h) * 2048 + s) * 64 + hd] = (__bf16)v;
                    } else if (cls == 1) {
                        Ko[((size_t)(b * 16 + h) * 2048 + s) * 64 + hd] = (__bf16)v;
                    } else {
                        Vo[((size_t)(b * 16 + h) * 64 + hd) * 2048 + s] = (__bf16)v;
                    }
                }
        }
    } else {
#pragma unroll
        for (int j = 0; j < 4; ++j) {
            const int e = n0 + wn + j * 16 + (l & 15);
            const float bv = b0[e];
#pragma unroll
            for (int i = 0; i < 4; ++i)
#pragma unroll
                for (int r = 0; r < 4; ++r) {
                    const int m = m0 + wm + i * 16 + ((l >> 4) << 2) + r;
                    Fo[(size_t)m * 1024 + e] = acc[i][j][r] + bv;
                }
        }
    }
}

// Flash attention, causal, SWAPPED-operand form: S^T = mfma(K,Q), O^T = mfma(VT,P^T).
// Each lane owns ONE q row (q = qw + (l&15)): softmax max/sum are in-register trees +
// 2 shuffles; m/l are per-lane scalars; P written as b64 packs; defer-max (T13).
// Q/K: [bh][s][64] bf16 (Q pre-scaled), VT: [bh][64][s] bf16, O: [b][s][h*64+hd] bf16.
__global__ __launch_bounds__(512) void attn_fwd(
    const __bf16* __restrict__ Qb, const __bf16* __restrict__ Kb,
    const __bf16* __restrict__ VTb, __bf16* __restrict__ Ob) {
    __shared__ __align__(16) __bf16 Ks[2][64 * 64];
    __shared__ __align__(16) __bf16 Vs[2][64 * 64];
    __shared__ __align__(16) __bf16 Ps[8 * 16 * 64];
    const int t = threadIdx.x, l = t & 63, w = t >> 6;
    const int qt = (int)gridDim.x - 1 - (int)blockIdx.x; // reversed: heavy blocks first
    const int bh = blockIdx.y;
    const int qw = qt * 128 + w * 16;
    const int qg = qw + (l & 15); // this lane's q row

    const __bf16* Qg = Qb + (size_t)bh * S_ * 64;
    const __bf16* Kg = Kb + (size_t)bh * S_ * 64;
    const __bf16* Vg = VTb + (size_t)bh * 64 * S_;

    bf16x8 qf[2];
    qf[0] = *reinterpret_cast<const bf16x8*>(Qg + (size_t)qg * 64 + (l >> 4) * 8);
    qf[1] = *reinterpret_cast<const bf16x8*>(Qg + (size_t)qg * 64 + 32 + (l >> 4) * 8);

    f32x4 o_acc[4] = {};
    float m_r = -INFINITY; // running max for q = qg (log2 domain)
    float l_r = 0.f;       // running denom

    char* Pw = reinterpret_cast<char*>(&Ps[w * 16 * 64]);

    // staging: 512 16B chunks each for K and VT; dest linear, source pre-swizzled (involution)
    const int srow = t >> 3, sc = t & 7;
    const __bf16* Ksrc = Kg + (size_t)srow * 64 + ((sc ^ (srow & 7)) * 8);
    const __bf16* Vsrc = Vg + (size_t)srow * S_ + ((sc ^ (srow & 7)) * 8);
    __bf16* Kd0 = &Ks[0][(w * 64) * 8];
    __bf16* Kd1 = &Ks[1][(w * 64) * 8];
    __bf16* Vd0 = &Vs[0][(w * 64) * 8];
    __bf16* Vd1 = &Vs[1][(w * 64) * 8];

    const int ktmax = 2 * qt + 1;
    gload16(Ksrc, Kd0);
    gload16(Vsrc, Vd0);
    int cur = 0;
    for (int kt = 0; kt <= ktmax; ++kt) {
        if (kt < ktmax) {
            gload16(Ksrc + (size_t)(kt + 1) * 4096, (cur == 0) ? Kd1 : Kd0);
            gload16(Vsrc + (kt + 1) * 64, (cur == 0) ? Vd1 : Vd0);
            asm volatile("s_waitcnt vmcnt(2)" ::: "memory"); // tile kt complete, kt+1 in flight
        } else {
            asm volatile("s_waitcnt vmcnt(0)" ::: "memory");
        }
        __builtin_amdgcn_s_barrier();
        const char* kb = (cur == 0) ? (const char*)Ks[0] : (const char*)Ks[1];
        const char* vb = (cur == 0) ? (const char*)Vs[0] : (const char*)Vs[1];
        if (kt * 64 <= qw + 15) { // wave has at least one unmasked row
            // S^T = K Q^T : lane gets S[q = l&15][kv = j*16 + (l>>4)*4 + r]
            f32x4 sa[4] = {};
            __builtin_amdgcn_s_setprio(1);
#pragma unroll
            for (int kk = 0; kk < 2; ++kk) {
#pragma unroll
                for (int j = 0; j < 4; ++j) {
                    const int row = j * 16 + (l & 15);
                    int byt = row * 128 + (kk * 32 + (l >> 4) * 8) * 2;
                    byt ^= (row & 7) << 4;
                    bf16x8 kf = *reinterpret_cast<const bf16x8*>(kb + byt);
                    sa[j] = __builtin_amdgcn_mfma_f32_16x16x32_bf16(kf, qf[kk], sa[j], 0, 0, 0);
                }
            }
            __builtin_amdgcn_s_setprio(0);
            // causal mask (scale already folded into Q)
            float p[4][4];
            const bool bnd = (kt * 64 + 63) > qw; // only boundary tiles need masking
#pragma unroll
            for (int j = 0; j < 4; ++j) {
                const int kv0 = kt * 64 + j * 16 + ((l >> 4) << 2);
#pragma unroll
                for (int r = 0; r < 4; ++r) {
                    float x = sa[j][r];
                    if (bnd && (kv0 + r) > qg) x = -INFINITY;
                    p[j][r] = x;
                }
            }
            // row max: in-register tree + 2 shuffles
            float mt;
            {
                float a0 = fmaxf(fmaxf(p[0][0], p[0][1]), fmaxf(p[0][2], p[0][3]));
                float a1 = fmaxf(fmaxf(p[1][0], p[1][1]), fmaxf(p[1][2], p[1][3]));
                float a2 = fmaxf(fmaxf(p[2][0], p[2][1]), fmaxf(p[2][2], p[2][3]));
                float a3 = fmaxf(fmaxf(p[3][0], p[3][1]), fmaxf(p[3][2], p[3][3]));
                mt = fmaxf(fmaxf(a0, a1), fmaxf(a2, a3));
                mt = fmaxf(mt, __shfl_xor(mt, 16));
                mt = fmaxf(mt, __shfl_xor(mt, 32));
            }
            // defer-max (T13): skip rescale while growth <= 8 (values bounded by 2^8)
            if (!__all(mt - m_r <= 8.0f)) {
                const float mn = fmaxf(m_r, mt);
                const float al = exp2f(m_r - mn);
                m_r = mn;
                l_r *= al;
#pragma unroll
                for (int j = 0; j < 4; ++j)
#pragma unroll
                    for (int r = 0; r < 4; ++r) o_acc[j][r] *= al;
            }
            float sum = 0.f;
#pragma unroll
            for (int j = 0; j < 4; ++j)
#pragma unroll
                for (int r = 0; r < 4; ++r) {
                    const float e = exp2f(p[j][r] - m_r);
                    p[j][r] = e;
                    sum += e;
                }
            sum += __shfl_xor(sum, 16);
            sum += __shfl_xor(sum, 32);
            l_r += sum;
            // write P rows (q = l&15) as 8B packs, swizzled
#pragma unroll
            for (int j = 0; j < 4; ++j) {
                bf16x4 pk = { (__bf16)p[j][0], (__bf16)p[j][1], (__bf16)p[j][2], (__bf16)p[j][3] };
                int byt = (l & 15) * 128 + j * 32 + (l >> 4) * 8;
                byt ^= (l & 7) << 4;
                *reinterpret_cast<bf16x4*>(Pw + byt) = pk;
            }
            // O^T += VT P^T : lane gets O[q = l&15][hd = j*16 + (l>>4)*4 + r]
            __builtin_amdgcn_s_setprio(1);
#pragma unroll
            for (int kk = 0; kk < 2; ++kk) {
                int pb = (l & 15) * 128 + kk * 64 + (l >> 4) * 16;
                pb ^= (l & 7) << 4;
                bf16x8 pf = *reinterpret_cast<const bf16x8*>(Pw + pb);
#pragma unroll
                for (int j = 0; j < 4; ++j) {
                    const int hd = j * 16 + (l & 15);
                    int vb2 = hd * 128 + (kk * 32 + (l >> 4) * 8) * 2;
                    vb2 ^= (hd & 7) << 4;
                    bf16x8 vf = *reinterpret_cast<const bf16x8*>(vb + vb2);
                    o_acc[j] = __builtin_amdgcn_mfma_f32_16x16x32_bf16(vf, pf, o_acc[j], 0, 0, 0);
                }
            }
            __builtin_amdgcn_s_setprio(0);
        }
        __builtin_amdgcn_s_barrier(); // all reads of buf[cur] done before it is re-staged
        cur ^= 1;
    }
    const int b = bh >> 4, h = bh & 15;
    const float inv = 1.0f / l_r;
#pragma unroll
    for (int j = 0; j < 4; ++j) {
        bf16x4 ov = { (__bf16)(o_acc[j][0] * inv), (__bf16)(o_acc[j][1] * inv),
                      (__bf16)(o_acc[j][2] * inv), (__bf16)(o_acc[j][3] * inv) };
        const int hd = j * 16 + ((l >> 4) << 2);
        *reinterpret_cast<bf16x4*>(&Ob[(size_t)(b * 2048 + qg) * 1024 + h * 64 + hd]) = ov;
    }
}

extern "C" void kernel_launch(void* const* d_in, const int* in_sizes, int n_in,
                              void* d_out, int out_size, void* d_ws, size_t ws_size,
                              hipStream_t stream) {
    const float* x  = (const float*)d_in[0];
    const float* wq = (const float*)d_in[2];
    const float* bq = (const float*)d_in[3];
    const float* wk = (const float*)d_in[4];
    const float* bk = (const float*)d_in[5];
    const float* wv = (const float*)d_in[6];
    const float* bv = (const float*)d_in[7];
    const float* wo = (const float*)d_in[8];
    const float* bo = (const float*)d_in[9];
    float* out = (float*)d_out;

    char* ws = (char*)d_ws;
    __bf16* xb   = (__bf16*)(ws);                 // 8192x1024        = 16,777,216 B
    __bf16* wqkv = (__bf16*)(ws + 16777216);      // 3072x1024        =  6,291,456 B
    __bf16* wob  = (__bf16*)(ws + 23068672);      // 1024x1024        =  2,097,152 B
    __bf16* Qb   = (__bf16*)(ws + 25165824);      // 64x2048x64       = 16,777,216 B
    __bf16* Kb   = (__bf16*)(ws + 41943040);      // 64x2048x64       = 16,777,216 B
    __bf16* VTb  = (__bf16*)(ws + 58720256);      // 64x64x2048       = 16,777,216 B
    __bf16* Ob   = (__bf16*)(ws + 75497472);      // 8192x1024        = 16,777,216 B

    cast_f32_bf16<<<8192, 256, 0, stream>>>(x, xb, 2097152);
    cast_f32_bf16<<<1024, 256, 0, stream>>>(wq, wqkv, 262144);
    cast_f32_bf16<<<1024, 256, 0, stream>>>(wk, wqkv + 1048576, 262144);
    cast_f32_bf16<<<1024, 256, 0, stream>>>(wv, wqkv + 2097152, 262144);
    cast_f32_bf16<<<1024, 256, 0, stream>>>(wo, wob, 262144);

    gemm_bt<0><<<dim3(24, 64), 256, 0, stream>>>(xb, wqkv, bq, bk, bv, Qb, Kb, VTb, nullptr, 1024);
    attn_fwd<<<dim3(16, 64), 512, 0, stream>>>(Qb, Kb, VTb, Ob);
    gemm_bt<1><<<dim3(8, 64), 256, 0, stream>>>(Ob, wob, bo, nullptr, nullptr, nullptr, nullptr, nullptr, out, 1024);
}